// Round 12
// baseline (125.765 us; speedup 1.0000x reference)
//
#include <hip/hip_runtime.h>

// GnnLayer: out[50000,64] = leaky_relu((h[idx]/dist).reshape(N,2048) @ W + bias)
// v10: v8 structure (no prefetch — v9 proved the request pipe is saturated and
// per-wave ILP regresses) + int8 W (B-lines 4096 -> 2048 per block).
//  - h: shared-scale int8 per row (v8), 64B/row, 1 line/edge, L2-resident.
//  - W: int8 with per-(kn, column) scale = amax/126 over each 64x64 chunk,
//    computed block-locally in k_prep. Decode = same exact dec8i path as h:
//    (0x6400|(4b)) - 1536 = 4q exactly; one rounding at x(s/4) per column.
//  - B fragment load: uint2 (8B/lane). Per-kn column scales (f16 [kn][64],
//    4KB total, L2-hot) loaded 4-per-lane per kn.
//  - k_prep: coalesced h-quant (4 lanes/row, quad shfl amax) from v9 (kept).
// ws: [0,128KB) W int8 frags; [128KB,+4KB) W scales f16; [256KB,+3.2MB) h int8;
//     then posx [N]x16B {x,y,z,scale_h}.

#define N_NODES 50000
#define KN      32
#define FIN     64
#define FOUT    64
#define MTILE   64

typedef __attribute__((ext_vector_type(4))) float    f32x4;
typedef __attribute__((ext_vector_type(8))) _Float16 f16x8;

// 8 int8 codes (two uints) -> f16x8 of (1024 + 4*b); caller subtracts 1536
// and multiplies by the scale/4.
static __device__ __forceinline__ f16x8 dec8i(unsigned int x, unsigned int y) {
    union { unsigned int w[4]; f16x8 v; } r;
    unsigned int xh = x >> 16, yh = y >> 16;
    r.w[0] = 0x64006400u | ((x  & 0xFFu) << 2) | ((x  & 0xFF00u) << 10);
    r.w[1] = 0x64006400u | ((xh & 0xFFu) << 2) | ((xh & 0xFF00u) << 10);
    r.w[2] = 0x64006400u | ((y  & 0xFFu) << 2) | ((y  & 0xFF00u) << 10);
    r.w[3] = 0x64006400u | ((yh & 0xFFu) << 2) | ((yh & 0xFF00u) << 10);
    return r.v;
}

// Prep: blocks [0,32) -> int8 W fragments + per-(kn,col) scales;
// blocks [32,..) -> int8 h + posx (coalesced, 64 rows/block, 4 lanes/row).
__global__ void k_prep(const float* __restrict__ w, unsigned char* __restrict__ wq,
                       _Float16* __restrict__ wsc,
                       const float* __restrict__ h, unsigned char* __restrict__ hq,
                       const float* __restrict__ pos, float4* __restrict__ posx) {
    __shared__ float s_w[64 * 64];
    __shared__ float s_scale[64];
    const int tid = threadIdx.x;
    if (blockIdx.x < 32) {
        const int kn = blockIdx.x;      // W rows [kn*64, kn*64+64)
        for (int p = tid; p < 64 * 64; p += 256)
            s_w[p] = w[kn * 64 * 64 + p];
        __syncthreads();
        if (tid < 64) {                 // per-column amax over this kn-chunk
            float amax = 0.f;
            for (int r = 0; r < 64; ++r)
                amax = fmaxf(amax, fabsf(s_w[r * 64 + tid]));
            float s = fmaxf(amax, 1e-30f) * (1.0f / 126.0f);
            s_scale[tid] = s;
            wsc[kn * 64 + tid] = (_Float16)(s * 0.25f);
        }
        __syncthreads();
        // wq[((kn*2+jh)*4 + t)*512 + lane*8 + i] encodes
        //   W[kn*64 + q*16 + jh*8 + i][t*16 + lm],  q=lane>>4, lm=lane&15
        const int t = tid >> 6, lane = tid & 63;
        const int lm = lane & 15, q = lane >> 4;
        const float inv = 1.0f / s_scale[t * 16 + lm];
        #pragma unroll
        for (int jh = 0; jh < 2; ++jh) {
            union { unsigned char c[8]; uint2 u; } o;
            #pragma unroll
            for (int i = 0; i < 8; ++i) {
                float wv = s_w[(q * 16 + jh * 8 + i) * 64 + t * 16 + lm];
                int q8 = __float2int_rn(wv * inv);            // [-126,126]
                o.c[i] = (unsigned char)(q8 + 128);
            }
            *(uint2*)(wq + (size_t)((kn * 2 + jh) * 4 + t) * 512 + lane * 8) = o.u;
        }
    } else {
        const int r   = (blockIdx.x - 32) * 64 + (tid >> 2);  // node
        const int sub = tid & 3;                              // feature quarter
        if (r < N_NODES) {
            const float* hr = h + (size_t)r * FIN + sub * 16;
            float v[16];
            float amax = 0.f;
            #pragma unroll
            for (int i = 0; i < 4; ++i) {
                float4 t4 = ((const float4*)hr)[i];
                v[i * 4 + 0] = t4.x; v[i * 4 + 1] = t4.y;
                v[i * 4 + 2] = t4.z; v[i * 4 + 3] = t4.w;
                amax = fmaxf(amax, fmaxf(fmaxf(fabsf(t4.x), fabsf(t4.y)),
                                         fmaxf(fabsf(t4.z), fabsf(t4.w))));
            }
            amax = fmaxf(amax, __shfl_xor(amax, 1));
            amax = fmaxf(amax, __shfl_xor(amax, 2));
            float scale = fmaxf(amax, 1e-30f) * (1.0f / 126.0f);
            float inv   = 126.0f / fmaxf(amax, 1e-30f);
            union { unsigned char c[16]; uint4 u4; } o;
            #pragma unroll
            for (int i = 0; i < 16; ++i) {
                int q8 = __float2int_rn(v[i] * inv);          // [-126,126]
                o.c[i] = (unsigned char)(q8 + 128);
            }
            *(uint4*)(hq + (size_t)r * 64 + sub * 16) = o.u4;
            if (sub == 0) {
                float4 px;
                px.x = pos[r * 3 + 0]; px.y = pos[r * 3 + 1]; px.z = pos[r * 3 + 2];
                px.w = scale;
                posx[r] = px;
            }
        }
    }
}

__global__ __launch_bounds__(256, 4) void k_main(
        const unsigned char* __restrict__ hq,   // int8 h [N][64]
        const float4*        __restrict__ posx, // [N] {x,y,z,scale_h}
        const int*           __restrict__ nidx, // [N][32]
        const unsigned char* __restrict__ wq,   // int8 W fragments
        const _Float16*      __restrict__ wsc,  // f16 scales/4 [kn][64]
        const float*         __restrict__ bias, // [64]
        float*               __restrict__ out)  // [N][64]
{
    // Union: phase 0 + main loop use s_e (16KB); reduction reuses as s_red.
    __shared__ __align__(16) char smem[2 * 64 * 68 * 4];
    int2*  s_e   = (int2*)smem;            // [kn][m] {idx, c1 bits (f32)}
    float* s_red = (float*)smem;           // 2 regions of [64][68]

    const int tid = threadIdx.x;
    const int m0  = blockIdx.x * MTILE;

    // Phase 0: per-edge {neighbor idx, c1 = scale_h*(1/dist)/4}.
    for (int p = tid; p < MTILE * KN; p += 256) {
        int m = p & 63, k = p >> 6;
        int node = m0 + m;
        int idx = 0; float c1 = 0.f;
        if (node < N_NODES) {
            idx = nidx[node * KN + k];
            float4 pn = posx[node];
            float4 pi = posx[idx];
            float dx = pn.x - pi.x, dy = pn.y - pi.y, dz = pn.z - pi.z;
            float sq = dx * dx + dy * dy + dz * dz;
            float scl = (sq == 0.f) ? 2.0f : rsqrtf(sq);  // ref: dist=0.5 at sq==0
            c1 = pi.w * scl * 0.25f;
        }
        s_e[k * MTILE + m] = make_int2(idx, __float_as_int(c1));
    }
    __syncthreads();

    const int lane = tid & 63, kg = tid >> 6;   // wave kg: kn in [kg*8, kg*8+8)
    const int lm = lane & 15, q = lane >> 4;

    f32x4 acc[4][4] = {};  // [m-tile][n-tile]

    #pragma unroll 1
    for (int j = 0; j < 8; ++j) {
        const int kn = kg * 8 + j;
        int2 e0 = s_e[kn * MTILE + lm];
        int2 e1 = s_e[kn * MTILE + 16 + lm];
        int2 e2 = s_e[kn * MTILE + 32 + lm];
        int2 e3 = s_e[kn * MTILE + 48 + lm];
        // ONE 16B load per edge: features q*16 .. q*16+16 (covers both jh).
        uint4 d0 = *(const uint4*)(hq + (size_t)e0.x * 64 + q * 16);
        uint4 d1 = *(const uint4*)(hq + (size_t)e1.x * 64 + q * 16);
        uint4 d2 = *(const uint4*)(hq + (size_t)e2.x * 64 + q * 16);
        uint4 d3 = *(const uint4*)(hq + (size_t)e3.x * 64 + q * 16);
        const _Float16 c0 = (_Float16)__int_as_float(e0.y);
        const _Float16 c1 = (_Float16)__int_as_float(e1.y);
        const _Float16 c2 = (_Float16)__int_as_float(e2.y);
        const _Float16 c3 = (_Float16)__int_as_float(e3.y);
        // Per-column B scales (scale/4) for this kn.
        const _Float16* wsk = wsc + kn * 64;
        const _Float16 sb0 = wsk[lm];
        const _Float16 sb1 = wsk[16 + lm];
        const _Float16 sb2 = wsk[32 + lm];
        const _Float16 sb3 = wsk[48 + lm];
        const _Float16 K = (_Float16)1536.0f;

        {   // jh = 0: features q*16 + 0..8 (A bytes d.x, d.y)
            const unsigned char* pq = wq + (size_t)((kn * 2 + 0) * 4) * 512 + lane * 8;
            uint2 w0 = *(const uint2*)(pq);
            uint2 w1 = *(const uint2*)(pq + 512);
            uint2 w2 = *(const uint2*)(pq + 1024);
            uint2 w3 = *(const uint2*)(pq + 1536);
            f16x8 b0 = (dec8i(w0.x, w0.y) - K) * sb0;
            f16x8 b1 = (dec8i(w1.x, w1.y) - K) * sb1;
            f16x8 b2 = (dec8i(w2.x, w2.y) - K) * sb2;
            f16x8 b3 = (dec8i(w3.x, w3.y) - K) * sb3;
            f16x8 a0 = (dec8i(d0.x, d0.y) - K) * c0;
            f16x8 a1 = (dec8i(d1.x, d1.y) - K) * c1;
            f16x8 a2 = (dec8i(d2.x, d2.y) - K) * c2;
            f16x8 a3 = (dec8i(d3.x, d3.y) - K) * c3;
            acc[0][0] = __builtin_amdgcn_mfma_f32_16x16x32_f16(a0, b0, acc[0][0], 0, 0, 0);
            acc[0][1] = __builtin_amdgcn_mfma_f32_16x16x32_f16(a0, b1, acc[0][1], 0, 0, 0);
            acc[0][2] = __builtin_amdgcn_mfma_f32_16x16x32_f16(a0, b2, acc[0][2], 0, 0, 0);
            acc[0][3] = __builtin_amdgcn_mfma_f32_16x16x32_f16(a0, b3, acc[0][3], 0, 0, 0);
            acc[1][0] = __builtin_amdgcn_mfma_f32_16x16x32_f16(a1, b0, acc[1][0], 0, 0, 0);
            acc[1][1] = __builtin_amdgcn_mfma_f32_16x16x32_f16(a1, b1, acc[1][1], 0, 0, 0);
            acc[1][2] = __builtin_amdgcn_mfma_f32_16x16x32_f16(a1, b2, acc[1][2], 0, 0, 0);
            acc[1][3] = __builtin_amdgcn_mfma_f32_16x16x32_f16(a1, b3, acc[1][3], 0, 0, 0);
            acc[2][0] = __builtin_amdgcn_mfma_f32_16x16x32_f16(a2, b0, acc[2][0], 0, 0, 0);
            acc[2][1] = __builtin_amdgcn_mfma_f32_16x16x32_f16(a2, b1, acc[2][1], 0, 0, 0);
            acc[2][2] = __builtin_amdgcn_mfma_f32_16x16x32_f16(a2, b2, acc[2][2], 0, 0, 0);
            acc[2][3] = __builtin_amdgcn_mfma_f32_16x16x32_f16(a2, b3, acc[2][3], 0, 0, 0);
            acc[3][0] = __builtin_amdgcn_mfma_f32_16x16x32_f16(a3, b0, acc[3][0], 0, 0, 0);
            acc[3][1] = __builtin_amdgcn_mfma_f32_16x16x32_f16(a3, b1, acc[3][1], 0, 0, 0);
            acc[3][2] = __builtin_amdgcn_mfma_f32_16x16x32_f16(a3, b2, acc[3][2], 0, 0, 0);
            acc[3][3] = __builtin_amdgcn_mfma_f32_16x16x32_f16(a3, b3, acc[3][3], 0, 0, 0);
        }
        {   // jh = 1: features q*16 + 8..16 (A bytes d.z, d.w)
            const unsigned char* pq = wq + (size_t)((kn * 2 + 1) * 4) * 512 + lane * 8;
            uint2 w0 = *(const uint2*)(pq);
            uint2 w1 = *(const uint2*)(pq + 512);
            uint2 w2 = *(const uint2*)(pq + 1024);
            uint2 w3 = *(const uint2*)(pq + 1536);
            f16x8 b0 = (dec8i(w0.x, w0.y) - K) * sb0;
            f16x8 b1 = (dec8i(w1.x, w1.y) - K) * sb1;
            f16x8 b2 = (dec8i(w2.x, w2.y) - K) * sb2;
            f16x8 b3 = (dec8i(w3.x, w3.y) - K) * sb3;
            f16x8 a0 = (dec8i(d0.z, d0.w) - K) * c0;
            f16x8 a1 = (dec8i(d1.z, d1.w) - K) * c1;
            f16x8 a2 = (dec8i(d2.z, d2.w) - K) * c2;
            f16x8 a3 = (dec8i(d3.z, d3.w) - K) * c3;
            acc[0][0] = __builtin_amdgcn_mfma_f32_16x16x32_f16(a0, b0, acc[0][0], 0, 0, 0);
            acc[0][1] = __builtin_amdgcn_mfma_f32_16x16x32_f16(a0, b1, acc[0][1], 0, 0, 0);
            acc[0][2] = __builtin_amdgcn_mfma_f32_16x16x32_f16(a0, b2, acc[0][2], 0, 0, 0);
            acc[0][3] = __builtin_amdgcn_mfma_f32_16x16x32_f16(a0, b3, acc[0][3], 0, 0, 0);
            acc[1][0] = __builtin_amdgcn_mfma_f32_16x16x32_f16(a1, b0, acc[1][0], 0, 0, 0);
            acc[1][1] = __builtin_amdgcn_mfma_f32_16x16x32_f16(a1, b1, acc[1][1], 0, 0, 0);
            acc[1][2] = __builtin_amdgcn_mfma_f32_16x16x32_f16(a1, b2, acc[1][2], 0, 0, 0);
            acc[1][3] = __builtin_amdgcn_mfma_f32_16x16x32_f16(a1, b3, acc[1][3], 0, 0, 0);
            acc[2][0] = __builtin_amdgcn_mfma_f32_16x16x32_f16(a2, b0, acc[2][0], 0, 0, 0);
            acc[2][1] = __builtin_amdgcn_mfma_f32_16x16x32_f16(a2, b1, acc[2][1], 0, 0, 0);
            acc[2][2] = __builtin_amdgcn_mfma_f32_16x16x32_f16(a2, b2, acc[2][2], 0, 0, 0);
            acc[2][3] = __builtin_amdgcn_mfma_f32_16x16x32_f16(a2, b3, acc[2][3], 0, 0, 0);
            acc[3][0] = __builtin_amdgcn_mfma_f32_16x16x32_f16(a3, b0, acc[3][0], 0, 0, 0);
            acc[3][1] = __builtin_amdgcn_mfma_f32_16x16x32_f16(a3, b1, acc[3][1], 0, 0, 0);
            acc[3][2] = __builtin_amdgcn_mfma_f32_16x16x32_f16(a3, b2, acc[3][2], 0, 0, 0);
            acc[3][3] = __builtin_amdgcn_mfma_f32_16x16x32_f16(a3, b3, acc[3][3], 0, 0, 0);
        }
    }

    // Main loop done reading s_e; barrier before aliased s_red writes.
    __syncthreads();

    // 2-stage pairwise cross-wave K-reduction (4 partials -> 2 regions).
    // C/D layout: col = lane&15 (n), row = q*4 + r. Global row = mt*16 + row.
    float* reg = s_red + (kg & 1) * (64 * 68);
    if (kg < 2) {
        #pragma unroll
        for (int mt = 0; mt < 4; ++mt)
            #pragma unroll
            for (int t = 0; t < 4; ++t)
                #pragma unroll
                for (int r = 0; r < 4; ++r)
                    reg[(mt * 16 + q * 4 + r) * 68 + t * 16 + lm] = acc[mt][t][r];
    }
    __syncthreads();
    if (kg >= 2) {
        #pragma unroll
        for (int mt = 0; mt < 4; ++mt)
            #pragma unroll
            for (int t = 0; t < 4; ++t)
                #pragma unroll
                for (int r = 0; r < 4; ++r)
                    reg[(mt * 16 + q * 4 + r) * 68 + t * 16 + lm] += acc[mt][t][r];
    }
    __syncthreads();

    // Epilogue: region0 + region1 + bias, leaky_relu, coalesced f32x4 stores.
    const int row = tid >> 2, c0e = (tid & 3) * 16;
    const int node = m0 + row;
    if (node < N_NODES) {
        #pragma unroll
        for (int i = 0; i < 4; ++i) {
            int c = c0e + i * 4;
            f32x4 v0 = *(const f32x4*)(s_red + row * 68 + c);
            f32x4 v1 = *(const f32x4*)(s_red + 64 * 68 + row * 68 + c);
            f32x4 bb = *(const f32x4*)(bias + c);
            f32x4 o = v0 + v1 + bb;
            #pragma unroll
            for (int jj = 0; jj < 4; ++jj) o[jj] = o[jj] > 0.f ? o[jj] : 0.01f * o[jj];
            *(f32x4*)(out + node * FOUT + c) = o;
        }
    }
}

extern "C" void kernel_launch(void* const* d_in, const int* in_sizes, int n_in,
                              void* d_out, int out_size, void* d_ws, size_t ws_size,
                              hipStream_t stream) {
    const float* h    = (const float*)d_in[0];
    const float* pos  = (const float*)d_in[1];
    const int*   nidx = (const int*)d_in[2];
    const float* w    = (const float*)d_in[3];
    const float* bias = (const float*)d_in[4];
    float* out = (float*)d_out;

    unsigned char* wq   = (unsigned char*)d_ws;                       // 128 KB
    _Float16*      wsc  = (_Float16*)((char*)d_ws + 131072);          // 4 KB
    unsigned char* hq   = (unsigned char*)d_ws + 262144;              // 3.2 MB
    float4*        posx = (float4*)((char*)d_ws + 262144 + 3200000);  // 800 KB

    const int h_blocks = (N_NODES + 63) / 64;                         // 782
    k_prep<<<32 + h_blocks, 256, 0, stream>>>(w, wq, wsc, h, hq, pos, posx);
    k_main<<<(N_NODES + MTILE - 1) / MTILE, 256, 0, stream>>>(hq, posx, nidx, wq, wsc, bias, out);
}

// Round 13
// 114.065 us; speedup vs baseline: 1.1026x; 1.1026x over previous
//
#include <hip/hip_runtime.h>

// GnnLayer: out[50000,64] = leaky_relu((h[idx]/dist).reshape(N,2048) @ W + bias)
// v11: v8 math (int8 h + f16 W — v10's int8 W reverted: decode VALU in the MFMA
// dep chain cost more than the L2-resident B lines it saved) + barrier-free
// per-wave phase 0:
//  - wave kg computes only its own 512 edge records (kn in [kg*8,kg*8+8)),
//    k-major: nidx reads 32B-contiguous (4x fewer line touches), posx[node]
//    amortized; NO __syncthreads between phase 0 and main loop (each wave
//    reads only the s_e columns it wrote). Wave gather bursts de-synchronize.
//  - s_e layout [m][kn], row stride 35 int2: main-loop reads conflict-free.
// ws: [0,256KB) W frags f16; [256KB,+3.2MB) h int8; then posx [N]x16B.

#define N_NODES 50000
#define KN      32
#define FIN     64
#define FOUT    64
#define MTILE   64
#define EPITCH  35   // s_e row stride (int2) — conflict-free main-loop reads

typedef __attribute__((ext_vector_type(4))) float    f32x4;
typedef __attribute__((ext_vector_type(8))) _Float16 f16x8;

// 8 int8 codes (two uints) -> f16x8 of (1024 + 4*b); caller subtracts 1536
// and multiplies by c1 (one rounding total — decode is exact).
static __device__ __forceinline__ f16x8 dec8i(unsigned int x, unsigned int y) {
    union { unsigned int w[4]; f16x8 v; } r;
    unsigned int xh = x >> 16, yh = y >> 16;
    r.w[0] = 0x64006400u | ((x  & 0xFFu) << 2) | ((x  & 0xFF00u) << 10);
    r.w[1] = 0x64006400u | ((xh & 0xFFu) << 2) | ((xh & 0xFF00u) << 10);
    r.w[2] = 0x64006400u | ((y  & 0xFFu) << 2) | ((y  & 0xFF00u) << 10);
    r.w[3] = 0x64006400u | ((yh & 0xFFu) << 2) | ((yh & 0xFF00u) << 10);
    return r.v;
}

// Prep: blocks [0,32) -> f16 W fragments (v8 layout); blocks [32,..) ->
// int8 h + posx (coalesced: 64 rows/block, 4 lanes/row).
__global__ void k_prep(const float* __restrict__ w, _Float16* __restrict__ wf,
                       const float* __restrict__ h, unsigned char* __restrict__ hq,
                       const float* __restrict__ pos, float4* __restrict__ posx) {
    __shared__ float s_w[64 * 64];
    const int tid = threadIdx.x;
    if (blockIdx.x < 32) {
        // wf[((kn*2+jh)*4 + t)*512 + lane*8 + i]
        //   = W[kn*64 + q*16 + jh*8 + i][t*16 + lm],  q=lane>>4, lm=lane&15
        const int kn = blockIdx.x;
        for (int p = tid; p < 64 * 64; p += 256)
            s_w[p] = w[kn * 64 * 64 + p];
        __syncthreads();
        const int t = tid >> 6, lane = tid & 63;
        const int lm = lane & 15, q = lane >> 4;
        #pragma unroll
        for (int jh = 0; jh < 2; ++jh) {
            f16x8 o;
            #pragma unroll
            for (int i = 0; i < 8; ++i)
                o[i] = (_Float16)s_w[(q * 16 + jh * 8 + i) * 64 + t * 16 + lm];
            *(f16x8*)(wf + ((kn * 2 + jh) * 4 + t) * 512 + lane * 8) = o;
        }
    } else {
        const int r   = (blockIdx.x - 32) * 64 + (tid >> 2);  // node
        const int sub = tid & 3;                              // feature quarter
        if (r < N_NODES) {
            const float* hr = h + (size_t)r * FIN + sub * 16;
            float v[16];
            float amax = 0.f;
            #pragma unroll
            for (int i = 0; i < 4; ++i) {
                float4 t4 = ((const float4*)hr)[i];
                v[i * 4 + 0] = t4.x; v[i * 4 + 1] = t4.y;
                v[i * 4 + 2] = t4.z; v[i * 4 + 3] = t4.w;
                amax = fmaxf(amax, fmaxf(fmaxf(fabsf(t4.x), fabsf(t4.y)),
                                         fmaxf(fabsf(t4.z), fabsf(t4.w))));
            }
            amax = fmaxf(amax, __shfl_xor(amax, 1));
            amax = fmaxf(amax, __shfl_xor(amax, 2));
            float scale = fmaxf(amax, 1e-30f) * (1.0f / 126.0f);
            float inv   = 126.0f / fmaxf(amax, 1e-30f);
            union { unsigned char c[16]; uint4 u4; } o;
            #pragma unroll
            for (int i = 0; i < 16; ++i) {
                int q8 = __float2int_rn(v[i] * inv);          // [-126,126]
                o.c[i] = (unsigned char)(q8 + 128);
            }
            *(uint4*)(hq + (size_t)r * 64 + sub * 16) = o.u4;
            if (sub == 0) {
                float4 px;
                px.x = pos[r * 3 + 0]; px.y = pos[r * 3 + 1]; px.z = pos[r * 3 + 2];
                px.w = scale;
                posx[r] = px;
            }
        }
    }
}

__global__ __launch_bounds__(256, 4) void k_main(
        const unsigned char* __restrict__ hq,   // int8 h [N][64]
        const float4*        __restrict__ posx, // [N] {x,y,z,scale_h}
        const int*           __restrict__ nidx, // [N][32]
        const _Float16*      __restrict__ wf,   // f16 W fragments
        const float*         __restrict__ bias, // [64]
        float*               __restrict__ out)  // [N][64]
{
    // Union: phase 0 + main loop use s_e ([64][EPITCH] int2, 17.9KB);
    // reduction reuses the same memory as s_red (34.8KB), barrier-separated.
    __shared__ __align__(16) char smem[2 * 64 * 68 * 4];
    int2*  s_e   = (int2*)smem;            // [m][kn] {idx, c1 bits}, stride EPITCH
    float* s_red = (float*)smem;           // 2 regions of [64][68]

    const int tid = threadIdx.x;
    const int m0  = blockIdx.x * MTILE;
    const int lane = tid & 63, kg = tid >> 6;   // wave kg: kn in [kg*8, kg*8+8)
    const int lm = lane & 15, q = lane >> 4;

    // Phase 0 (PER-WAVE, no barrier): wave kg computes its own 512 edges,
    // k-major so nidx reads are 32B-contiguous per node.
    for (int it = 0; it < 8; ++it) {
        int pp = it * 64 + lane;        // 0..511
        int m  = pp >> 3;
        int kn = kg * 8 + (pp & 7);
        int node = m0 + m;
        int idx = 0; float c1 = 0.f;
        if (node < N_NODES) {
            idx = nidx[node * KN + kn];
            float4 pn = posx[node];
            float4 pi = posx[idx];
            float dx = pn.x - pi.x, dy = pn.y - pi.y, dz = pn.z - pi.z;
            float sq = dx * dx + dy * dy + dz * dz;
            float scl = (sq == 0.f) ? 2.0f : rsqrtf(sq);  // ref: dist=0.5 at sq==0
            c1 = pi.w * scl * 0.25f;
        }
        s_e[m * EPITCH + kn] = make_int2(idx, __float_as_int(c1));
    }
    // No __syncthreads: each wave reads only the s_e columns it wrote.

    const _Float16* pb = wf + lane * 8;

    f32x4 acc[4][4] = {};  // [m-tile][n-tile]

    #pragma unroll 1
    for (int j = 0; j < 8; ++j) {
        const int kn = kg * 8 + j;
        int2 e0 = s_e[(lm     ) * EPITCH + kn];
        int2 e1 = s_e[(lm + 16) * EPITCH + kn];
        int2 e2 = s_e[(lm + 32) * EPITCH + kn];
        int2 e3 = s_e[(lm + 48) * EPITCH + kn];
        // ONE 16B load per edge: features q*16 .. q*16+16 (covers both jh).
        uint4 d0 = *(const uint4*)(hq + (size_t)e0.x * 64 + q * 16);
        uint4 d1 = *(const uint4*)(hq + (size_t)e1.x * 64 + q * 16);
        uint4 d2 = *(const uint4*)(hq + (size_t)e2.x * 64 + q * 16);
        uint4 d3 = *(const uint4*)(hq + (size_t)e3.x * 64 + q * 16);
        const _Float16 c0 = (_Float16)__int_as_float(e0.y);
        const _Float16 c1 = (_Float16)__int_as_float(e1.y);
        const _Float16 c2 = (_Float16)__int_as_float(e2.y);
        const _Float16 c3 = (_Float16)__int_as_float(e3.y);
        const _Float16 K = (_Float16)1536.0f;

        {   // jh = 0: features q*16 + 0..8 (A bytes d.x, d.y)
            const _Float16* pbb = pb + (kn * 2 + 0) * 2048;
            f16x8 b0 = *(const f16x8*)(pbb);
            f16x8 b1 = *(const f16x8*)(pbb + 512);
            f16x8 b2 = *(const f16x8*)(pbb + 1024);
            f16x8 b3 = *(const f16x8*)(pbb + 1536);
            f16x8 a0 = (dec8i(d0.x, d0.y) - K) * c0;
            f16x8 a1 = (dec8i(d1.x, d1.y) - K) * c1;
            f16x8 a2 = (dec8i(d2.x, d2.y) - K) * c2;
            f16x8 a3 = (dec8i(d3.x, d3.y) - K) * c3;
            acc[0][0] = __builtin_amdgcn_mfma_f32_16x16x32_f16(a0, b0, acc[0][0], 0, 0, 0);
            acc[0][1] = __builtin_amdgcn_mfma_f32_16x16x32_f16(a0, b1, acc[0][1], 0, 0, 0);
            acc[0][2] = __builtin_amdgcn_mfma_f32_16x16x32_f16(a0, b2, acc[0][2], 0, 0, 0);
            acc[0][3] = __builtin_amdgcn_mfma_f32_16x16x32_f16(a0, b3, acc[0][3], 0, 0, 0);
            acc[1][0] = __builtin_amdgcn_mfma_f32_16x16x32_f16(a1, b0, acc[1][0], 0, 0, 0);
            acc[1][1] = __builtin_amdgcn_mfma_f32_16x16x32_f16(a1, b1, acc[1][1], 0, 0, 0);
            acc[1][2] = __builtin_amdgcn_mfma_f32_16x16x32_f16(a1, b2, acc[1][2], 0, 0, 0);
            acc[1][3] = __builtin_amdgcn_mfma_f32_16x16x32_f16(a1, b3, acc[1][3], 0, 0, 0);
            acc[2][0] = __builtin_amdgcn_mfma_f32_16x16x32_f16(a2, b0, acc[2][0], 0, 0, 0);
            acc[2][1] = __builtin_amdgcn_mfma_f32_16x16x32_f16(a2, b1, acc[2][1], 0, 0, 0);
            acc[2][2] = __builtin_amdgcn_mfma_f32_16x16x32_f16(a2, b2, acc[2][2], 0, 0, 0);
            acc[2][3] = __builtin_amdgcn_mfma_f32_16x16x32_f16(a2, b3, acc[2][3], 0, 0, 0);
            acc[3][0] = __builtin_amdgcn_mfma_f32_16x16x32_f16(a3, b0, acc[3][0], 0, 0, 0);
            acc[3][1] = __builtin_amdgcn_mfma_f32_16x16x32_f16(a3, b1, acc[3][1], 0, 0, 0);
            acc[3][2] = __builtin_amdgcn_mfma_f32_16x16x32_f16(a3, b2, acc[3][2], 0, 0, 0);
            acc[3][3] = __builtin_amdgcn_mfma_f32_16x16x32_f16(a3, b3, acc[3][3], 0, 0, 0);
        }
        {   // jh = 1: features q*16 + 8..16 (A bytes d.z, d.w)
            const _Float16* pbb = pb + (kn * 2 + 1) * 2048;
            f16x8 b0 = *(const f16x8*)(pbb);
            f16x8 b1 = *(const f16x8*)(pbb + 512);
            f16x8 b2 = *(const f16x8*)(pbb + 1024);
            f16x8 b3 = *(const f16x8*)(pbb + 1536);
            f16x8 a0 = (dec8i(d0.z, d0.w) - K) * c0;
            f16x8 a1 = (dec8i(d1.z, d1.w) - K) * c1;
            f16x8 a2 = (dec8i(d2.z, d2.w) - K) * c2;
            f16x8 a3 = (dec8i(d3.z, d3.w) - K) * c3;
            acc[0][0] = __builtin_amdgcn_mfma_f32_16x16x32_f16(a0, b0, acc[0][0], 0, 0, 0);
            acc[0][1] = __builtin_amdgcn_mfma_f32_16x16x32_f16(a0, b1, acc[0][1], 0, 0, 0);
            acc[0][2] = __builtin_amdgcn_mfma_f32_16x16x32_f16(a0, b2, acc[0][2], 0, 0, 0);
            acc[0][3] = __builtin_amdgcn_mfma_f32_16x16x32_f16(a0, b3, acc[0][3], 0, 0, 0);
            acc[1][0] = __builtin_amdgcn_mfma_f32_16x16x32_f16(a1, b0, acc[1][0], 0, 0, 0);
            acc[1][1] = __builtin_amdgcn_mfma_f32_16x16x32_f16(a1, b1, acc[1][1], 0, 0, 0);
            acc[1][2] = __builtin_amdgcn_mfma_f32_16x16x32_f16(a1, b2, acc[1][2], 0, 0, 0);
            acc[1][3] = __builtin_amdgcn_mfma_f32_16x16x32_f16(a1, b3, acc[1][3], 0, 0, 0);
            acc[2][0] = __builtin_amdgcn_mfma_f32_16x16x32_f16(a2, b0, acc[2][0], 0, 0, 0);
            acc[2][1] = __builtin_amdgcn_mfma_f32_16x16x32_f16(a2, b1, acc[2][1], 0, 0, 0);
            acc[2][2] = __builtin_amdgcn_mfma_f32_16x16x32_f16(a2, b2, acc[2][2], 0, 0, 0);
            acc[2][3] = __builtin_amdgcn_mfma_f32_16x16x32_f16(a2, b3, acc[2][3], 0, 0, 0);
            acc[3][0] = __builtin_amdgcn_mfma_f32_16x16x32_f16(a3, b0, acc[3][0], 0, 0, 0);
            acc[3][1] = __builtin_amdgcn_mfma_f32_16x16x32_f16(a3, b1, acc[3][1], 0, 0, 0);
            acc[3][2] = __builtin_amdgcn_mfma_f32_16x16x32_f16(a3, b2, acc[3][2], 0, 0, 0);
            acc[3][3] = __builtin_amdgcn_mfma_f32_16x16x32_f16(a3, b3, acc[3][3], 0, 0, 0);
        }
    }

    // All waves done reading s_e; barrier before aliased s_red writes.
    __syncthreads();

    // 2-stage pairwise cross-wave K-reduction (4 partials -> 2 regions).
    // C/D layout: col = lane&15 (n), row = q*4 + r. Global row = mt*16 + row.
    float* reg = s_red + (kg & 1) * (64 * 68);
    if (kg < 2) {
        #pragma unroll
        for (int mt = 0; mt < 4; ++mt)
            #pragma unroll
            for (int t = 0; t < 4; ++t)
                #pragma unroll
                for (int r = 0; r < 4; ++r)
                    reg[(mt * 16 + q * 4 + r) * 68 + t * 16 + lm] = acc[mt][t][r];
    }
    __syncthreads();
    if (kg >= 2) {
        #pragma unroll
        for (int mt = 0; mt < 4; ++mt)
            #pragma unroll
            for (int t = 0; t < 4; ++t)
                #pragma unroll
                for (int r = 0; r < 4; ++r)
                    reg[(mt * 16 + q * 4 + r) * 68 + t * 16 + lm] += acc[mt][t][r];
    }
    __syncthreads();

    // Epilogue: region0 + region1 + bias, leaky_relu, coalesced f32x4 stores.
    const int row = tid >> 2, c0e = (tid & 3) * 16;
    const int node = m0 + row;
    if (node < N_NODES) {
        #pragma unroll
        for (int i = 0; i < 4; ++i) {
            int c = c0e + i * 4;
            f32x4 v0 = *(const f32x4*)(s_red + row * 68 + c);
            f32x4 v1 = *(const f32x4*)(s_red + 64 * 68 + row * 68 + c);
            f32x4 bb = *(const f32x4*)(bias + c);
            f32x4 o = v0 + v1 + bb;
            #pragma unroll
            for (int jj = 0; jj < 4; ++jj) o[jj] = o[jj] > 0.f ? o[jj] : 0.01f * o[jj];
            *(f32x4*)(out + node * FOUT + c) = o;
        }
    }
}

extern "C" void kernel_launch(void* const* d_in, const int* in_sizes, int n_in,
                              void* d_out, int out_size, void* d_ws, size_t ws_size,
                              hipStream_t stream) {
    const float* h    = (const float*)d_in[0];
    const float* pos  = (const float*)d_in[1];
    const int*   nidx = (const int*)d_in[2];
    const float* w    = (const float*)d_in[3];
    const float* bias = (const float*)d_in[4];
    float* out = (float*)d_out;

    _Float16*      wf   = (_Float16*)d_ws;                            // 256 KB
    unsigned char* hq   = (unsigned char*)d_ws + 262144;              // 3.2 MB
    float4*        posx = (float4*)((char*)d_ws + 262144 + 3200000);  // 800 KB

    const int h_blocks = (N_NODES + 63) / 64;                         // 782
    k_prep<<<32 + h_blocks, 256, 0, stream>>>(w, wf, h, hq, pos, posx);
    k_main<<<(N_NODES + MTILE - 1) / MTILE, 256, 0, stream>>>(hq, posx, nidx, wf, bias, out);
}